// Round 17
// baseline (50.507 us; speedup 1.0000x reference)
//
#include <hip/hip_runtime.h>

typedef float    f32x4 __attribute__((ext_vector_type(4)));
typedef _Float16 f16x8 __attribute__((ext_vector_type(8)));
typedef _Float16 f16x4 __attribute__((ext_vector_type(4)));
typedef _Float16 f16x2 __attribute__((ext_vector_type(2)));
typedef __fp16   fp16x2_raw __attribute__((ext_vector_type(2)));

#define MFMA16 __builtin_amdgcn_mfma_f32_16x16x32_f16

__device__ __forceinline__ f16x2 pkrtz(float a, float b) {
    fp16x2_raw t = __builtin_amdgcn_cvt_pkrtz(a, b);
    union { fp16x2_raw r; f16x2 h; } u;
    u.r = t;
    return u.h;
}
#define PKRTZ pkrtz

#define NQ     400
#define DMODEL 768

// streaming softmax, fixed offset: p = 2^(fma(S, SCL, pen[k]))
#define SCL 0.18033688011112042f   /* 0.125 * log2(e) */
#define PEN 18033.688011112043f    /* 12500 * log2(e) */
#define M0  8.0f

// LDS layout (bytes)
#define K_OFF    0                  // K fp16 [400][64perm], 128B rows, XOR-swizzled by (row&7)<<4
#define VT_OFF   51200              // V^T fp16 [64][424], 848B rows, k block-permuted; 54272B
#define W_OFF    105472             // W fp16 x3, [64] rows of 128B, XOR-swizzled; 24576B
#define PEN_OFF  130048             // f32[400] penalty table
#define BIAS_OFF 131648             // bias f32 [3][64]
#define MKB_OFF  132416             // mask bits, 16 u32
#define SMEM_BYTES 132480

__device__ __forceinline__ f16x8 cvt8(const float* rp) {
    f32x4 u0 = *(const f32x4*)(rp);
    f32x4 u1 = *(const f32x4*)(rp + 4);
    union { f16x2 h2[4]; f16x8 v; } u;
    u.h2[0] = PKRTZ(u0[0], u0[1]);
    u.h2[1] = PKRTZ(u0[2], u0[3]);
    u.h2[2] = PKRTZ(u1[0], u1[1]);
    u.h2[3] = PKRTZ(u1[2], u1[3]);
    return u.v;
}

// V projection (A=R-frag, B=Wv-frag) -> VT rows, b64 writes
__device__ __forceinline__ void proj_v(char* smem, f16x8 af0, f16x8 af1,
                                       int t, int g, int q16, int csw) {
    #pragma unroll
    for (int cg = 0; cg < 4; ++cg) {
        const int col = cg * 16 + q16;
        const float bb = *(const float*)(smem + BIAS_OFF + (128 + col) * 4);
        f32x4 acc = {bb, bb, bb, bb};
        f16x8 wb0 = *(const f16x8*)(smem + W_OFF + 16384 + col * 128 + ((g * 16) ^ csw));
        f16x8 wb1 = *(const f16x8*)(smem + W_OFF + 16384 + col * 128 + ((64 + g * 16) ^ csw));
        acc = MFMA16(af0, wb0, acc, 0, 0, 0);
        acc = MFMA16(af1, wb1, acc, 0, 0, 0);
        union { f16x2 h2[2]; f16x4 v; } hv;
        hv.h2[0] = PKRTZ(acc[0], acc[1]);
        hv.h2[1] = PKRTZ(acc[2], acc[3]);
        *(f16x4*)(smem + VT_OFF + col * 848 + (t >> 1) * 64 + g * 16 + (t & 1) * 8) = hv.v;
    }
}

// K projection (SWAPPED: A=Wk-frag, B=R-frag) -> K row kk, permuted cols, b64 writes
__device__ __forceinline__ void proj_k(char* smem, f16x8 af0, f16x8 af1,
                                       int kk, int g, int q16, int csw) {
    #pragma unroll
    for (int cg = 0; cg < 4; ++cg) {
        const int d0 = cg * 16 + 4 * g;
        f32x4 acc = *(const f32x4*)(smem + BIAS_OFF + (64 + d0) * 4);
        f16x8 wb0 = *(const f16x8*)(smem + W_OFF + 8192 + (cg * 16 + q16) * 128 + ((g * 16) ^ csw));
        f16x8 wb1 = *(const f16x8*)(smem + W_OFF + 8192 + (cg * 16 + q16) * 128 + ((64 + g * 16) ^ csw));
        acc = MFMA16(wb0, af0, acc, 0, 0, 0);   // C[d][q]
        acc = MFMA16(wb1, af1, acc, 0, 0, 0);
        union { f16x2 h2[2]; f16x4 v; } hv;
        hv.h2[0] = PKRTZ(acc[0], acc[1]);
        hv.h2[1] = PKRTZ(acc[2], acc[3]);
        const int pos2 = ((cg & 2) << 5) + g * 16 + (cg & 1) * 8;
        *(f16x4*)(smem + K_OFF + kk * 128 + (pos2 ^ csw)) = hv.v;
    }
}

// Q projection (SWAPPED) -> register B-fragments, permuted k-order
__device__ __forceinline__ void proj_q(char* smem, f16x8 af0, f16x8 af1,
                                       int g, int q16, int csw, f16x8 (&qreg)[2]) {
    f32x4 qa[4];
    #pragma unroll
    for (int cg = 0; cg < 4; ++cg) {
        const int d0 = cg * 16 + 4 * g;
        f32x4 acc = *(const f32x4*)(smem + BIAS_OFF + d0 * 4);
        f16x8 wb0 = *(const f16x8*)(smem + W_OFF + (cg * 16 + q16) * 128 + ((g * 16) ^ csw));
        f16x8 wb1 = *(const f16x8*)(smem + W_OFF + (cg * 16 + q16) * 128 + ((64 + g * 16) ^ csw));
        acc = MFMA16(wb0, af0, acc, 0, 0, 0);
        acc = MFMA16(wb1, af1, acc, 0, 0, 0);
        qa[cg] = acc;
    }
    union { f16x2 h2[4]; f16x8 v; } u0, u1;
    u0.h2[0] = PKRTZ(qa[0][0], qa[0][1]);
    u0.h2[1] = PKRTZ(qa[0][2], qa[0][3]);
    u0.h2[2] = PKRTZ(qa[1][0], qa[1][1]);
    u0.h2[3] = PKRTZ(qa[1][2], qa[1][3]);
    u1.h2[0] = PKRTZ(qa[2][0], qa[2][1]);
    u1.h2[1] = PKRTZ(qa[2][2], qa[2][3]);
    u1.h2[2] = PKRTZ(qa[3][0], qa[3][1]);
    u1.h2[3] = PKRTZ(qa[3][2], qa[3][3]);
    qreg[0] = u0.v;
    qreg[1] = u1.v;
}

// One head segment: fused phase 1 (K/V/Q from one R-tile load) + sync + phase 2.
// Q ownership = tiles {2wv, 2wv+1} clipped to [qlo,qhi). NOINLINE: each call is
// register-allocated independently (round-15 lesson: inlined segments merge
// pressure and spill).
__attribute__((noinline)) __device__
void run_seg(char* smem, const float* __restrict__ Rbh, float* __restrict__ outh,
             int qlo, int qhi, int wv, int g, int q16, int csw) {
    const int tA = 2 * wv, tB = 2 * wv + 1;
    const bool own0 = (tA >= qlo) && (tA < qhi);
    const bool own1 = (tB >= qlo) && (tB < qhi);
    f16x8 qreg0[2], qreg1[2];

    if (tA < 25) {
        const float* rp = Rbh + (size_t)(tA * 16 + q16) * DMODEL + g * 8;
        f16x8 af0 = cvt8(rp);
        f16x8 af1 = cvt8(rp + 32);
        proj_k(smem, af0, af1, tA * 16 + q16, g, q16, csw);
        proj_v(smem, af0, af1, tA, g, q16, csw);
        if (own0) proj_q(smem, af0, af1, g, q16, csw, qreg0);
    }
    if (tB < 25) {
        const float* rp = Rbh + (size_t)(tB * 16 + q16) * DMODEL + g * 8;
        f16x8 af0 = cvt8(rp);
        f16x8 af1 = cvt8(rp + 32);
        proj_k(smem, af0, af1, tB * 16 + q16, g, q16, csw);
        proj_v(smem, af0, af1, tB, g, q16, csw);
        if (own1) proj_q(smem, af0, af1, g, q16, csw, qreg1);
    }
    __syncthreads();

    int qt0 = own0 ? tA : (own1 ? tB : -1);
    const int qt1 = (own0 && own1) ? tB : -1;
    if (!own0 && own1) { qreg0[0] = qreg1[0]; qreg0[1] = qreg1[1]; }

    if (qt0 >= 0) {
        const bool has2 = (qt1 >= 0);
        const int qrow0 = qt0 * 16 + q16;
        const unsigned qb0 = (((const unsigned*)(smem + MKB_OFF))[qrow0 >> 5] >> (qrow0 & 31)) & 1u;
        const int qrow1 = (has2 ? qt1 : qt0) * 16 + q16;
        const unsigned qb1 = (((const unsigned*)(smem + MKB_OFF))[qrow1 >> 5] >> (qrow1 & 31)) & 1u;

        const int kbase = K_OFF + q16 * 128;
        const int o0 = (g * 16) ^ csw;
        const int o1 = (64 + g * 16) ^ csw;

        f32x4 oc0[4], oc1[4];
        #pragma unroll
        for (int cg = 0; cg < 4; ++cg) {
            oc0[cg] = (f32x4){0.f, 0.f, 0.f, 0.f};
            oc1[cg] = (f32x4){0.f, 0.f, 0.f, 0.f};
        }
        float ps0 = 0.f, ps1 = 0.f;

        // prefetch chunk 0, both tiles
        f16x8 ka0 = *(const f16x8*)(smem + kbase + o0);
        f16x8 ka1 = *(const f16x8*)(smem + kbase + o1);
        f16x8 kb0 = *(const f16x8*)(smem + kbase + 2048 + o0);
        f16x8 kb1 = *(const f16x8*)(smem + kbase + 2048 + o1);

        #pragma unroll 1
        for (int kc = 0; kc < 12; ++kc) {
            f32x4 pa4 = *(const f32x4*)(smem + PEN_OFF + (kc * 32 + 4 * g) * 4);
            f32x4 pb4 = *(const f32x4*)(smem + PEN_OFF + (kc * 32 + 16 + 4 * g) * 4);

            __builtin_amdgcn_s_setprio(1);
            f32x4 accA0 = {0.f, 0.f, 0.f, 0.f};
            accA0 = MFMA16(ka0, qreg0[0], accA0, 0, 0, 0);
            accA0 = MFMA16(ka1, qreg0[1], accA0, 0, 0, 0);
            f32x4 accB0 = {0.f, 0.f, 0.f, 0.f};
            accB0 = MFMA16(kb0, qreg0[0], accB0, 0, 0, 0);
            accB0 = MFMA16(kb1, qreg0[1], accB0, 0, 0, 0);
            f32x4 accA1 = {0.f, 0.f, 0.f, 0.f};
            f32x4 accB1 = {0.f, 0.f, 0.f, 0.f};
            if (has2) {
                accA1 = MFMA16(ka0, qreg1[0], accA1, 0, 0, 0);
                accA1 = MFMA16(ka1, qreg1[1], accA1, 0, 0, 0);
                accB1 = MFMA16(kb0, qreg1[0], accB1, 0, 0, 0);
                accB1 = MFMA16(kb1, qreg1[1], accB1, 0, 0, 0);
            }
            __builtin_amdgcn_s_setprio(0);

            // prefetch next chunk (kc=11: tileA = tail rows 384..399; tileB garbage, unused)
            const char* kn = smem + kbase + (kc + 1) * 4096;
            ka0 = *(const f16x8*)(kn + o0);
            ka1 = *(const f16x8*)(kn + o1);
            kb0 = *(const f16x8*)(kn + 2048 + o0);
            kb1 = *(const f16x8*)(kn + 2048 + o1);

            const float e0 = __builtin_amdgcn_exp2f(fmaf(accA0[0], SCL, pa4[0]));
            const float e1 = __builtin_amdgcn_exp2f(fmaf(accA0[1], SCL, pa4[1]));
            const float e2 = __builtin_amdgcn_exp2f(fmaf(accA0[2], SCL, pa4[2]));
            const float e3 = __builtin_amdgcn_exp2f(fmaf(accA0[3], SCL, pa4[3]));
            const float e4 = __builtin_amdgcn_exp2f(fmaf(accB0[0], SCL, pb4[0]));
            const float e5 = __builtin_amdgcn_exp2f(fmaf(accB0[1], SCL, pb4[1]));
            const float e6 = __builtin_amdgcn_exp2f(fmaf(accB0[2], SCL, pb4[2]));
            const float e7 = __builtin_amdgcn_exp2f(fmaf(accB0[3], SCL, pb4[3]));
            ps0 += ((e0 + e1) + (e2 + e3)) + ((e4 + e5) + (e6 + e7));
            union { f16x2 h2[4]; f16x8 v; } pu0;
            pu0.h2[0] = PKRTZ(e0, e1);
            pu0.h2[1] = PKRTZ(e2, e3);
            pu0.h2[2] = PKRTZ(e4, e5);
            pu0.h2[3] = PKRTZ(e6, e7);
            const f16x8 pfrag0 = pu0.v;

            f16x8 pfrag1;
            if (has2) {
                const float f0 = __builtin_amdgcn_exp2f(fmaf(accA1[0], SCL, pa4[0]));
                const float f1 = __builtin_amdgcn_exp2f(fmaf(accA1[1], SCL, pa4[1]));
                const float f2 = __builtin_amdgcn_exp2f(fmaf(accA1[2], SCL, pa4[2]));
                const float f3 = __builtin_amdgcn_exp2f(fmaf(accA1[3], SCL, pa4[3]));
                const float f4 = __builtin_amdgcn_exp2f(fmaf(accB1[0], SCL, pb4[0]));
                const float f5 = __builtin_amdgcn_exp2f(fmaf(accB1[1], SCL, pb4[1]));
                const float f6 = __builtin_amdgcn_exp2f(fmaf(accB1[2], SCL, pb4[2]));
                const float f7 = __builtin_amdgcn_exp2f(fmaf(accB1[3], SCL, pb4[3]));
                ps1 += ((f0 + f1) + (f2 + f3)) + ((f4 + f5) + (f6 + f7));
                union { f16x2 h2[4]; f16x8 v; } pu1;
                pu1.h2[0] = PKRTZ(f0, f1);
                pu1.h2[1] = PKRTZ(f2, f3);
                pu1.h2[2] = PKRTZ(f4, f5);
                pu1.h2[3] = PKRTZ(f6, f7);
                pfrag1 = pu1.v;
            }

            __builtin_amdgcn_s_setprio(1);
            #pragma unroll
            for (int cg = 0; cg < 4; ++cg) {
                f16x8 vb = *(const f16x8*)(smem + VT_OFF + (cg * 16 + q16) * 848 + kc * 64 + g * 16);
                oc0[cg] = MFMA16(pfrag0, vb, oc0[cg], 0, 0, 0);
                if (has2) oc1[cg] = MFMA16(pfrag1, vb, oc1[cg], 0, 0, 0);
            }
            __builtin_amdgcn_s_setprio(0);
        }
        // tail: tile 24 (keys 384..399) via last prefetch; upper half zero pad
        {
            f32x4 pa4 = *(const f32x4*)(smem + PEN_OFF + (384 + 4 * g) * 4);
            f32x4 accA0 = {0.f, 0.f, 0.f, 0.f};
            accA0 = MFMA16(ka0, qreg0[0], accA0, 0, 0, 0);
            accA0 = MFMA16(ka1, qreg0[1], accA0, 0, 0, 0);
            const float e0 = __builtin_amdgcn_exp2f(fmaf(accA0[0], SCL, pa4[0]));
            const float e1 = __builtin_amdgcn_exp2f(fmaf(accA0[1], SCL, pa4[1]));
            const float e2 = __builtin_amdgcn_exp2f(fmaf(accA0[2], SCL, pa4[2]));
            const float e3 = __builtin_amdgcn_exp2f(fmaf(accA0[3], SCL, pa4[3]));
            ps0 += (e0 + e1) + (e2 + e3);
            union { f16x2 h2[4]; f16x8 v; } pu0;
            pu0.h2[0] = PKRTZ(e0, e1);
            pu0.h2[1] = PKRTZ(e2, e3);
            pu0.h2[2] = (f16x2){0, 0};
            pu0.h2[3] = (f16x2){0, 0};
            const f16x8 pfrag0 = pu0.v;

            f16x8 pfrag1;
            if (has2) {
                f32x4 accA1 = {0.f, 0.f, 0.f, 0.f};
                accA1 = MFMA16(ka0, qreg1[0], accA1, 0, 0, 0);
                accA1 = MFMA16(ka1, qreg1[1], accA1, 0, 0, 0);
                const float f0 = __builtin_amdgcn_exp2f(fmaf(accA1[0], SCL, pa4[0]));
                const float f1 = __builtin_amdgcn_exp2f(fmaf(accA1[1], SCL, pa4[1]));
                const float f2 = __builtin_amdgcn_exp2f(fmaf(accA1[2], SCL, pa4[2]));
                const float f3 = __builtin_amdgcn_exp2f(fmaf(accA1[3], SCL, pa4[3]));
                ps1 += (f0 + f1) + (f2 + f3);
                union { f16x2 h2[4]; f16x8 v; } pu1;
                pu1.h2[0] = PKRTZ(f0, f1);
                pu1.h2[1] = PKRTZ(f2, f3);
                pu1.h2[2] = (f16x2){0, 0};
                pu1.h2[3] = (f16x2){0, 0};
                pfrag1 = pu1.v;
            }
            #pragma unroll
            for (int cg = 0; cg < 4; ++cg) {
                f16x8 vb = *(const f16x8*)(smem + VT_OFF + (cg * 16 + q16) * 848 + 12 * 64 + g * 16);
                oc0[cg] = MFMA16(pfrag0, vb, oc0[cg], 0, 0, 0);
                if (has2) oc1[cg] = MFMA16(pfrag1, vb, oc1[cg], 0, 0, 0);
            }
        }

        // row sums + epilogues
        ps0 += __shfl_xor(ps0, 16);
        ps0 += __shfl_xor(ps0, 32);
        const float myrs0 = qb0 ? __builtin_amdgcn_rcpf(ps0) : 0.0f;
        float rs[4];
        #pragma unroll
        for (int r = 0; r < 4; ++r) rs[r] = __shfl(myrs0, 4 * g + r);
        float* op0 = outh + (size_t)(qt0 * 16) * DMODEL;
        #pragma unroll
        for (int r = 0; r < 4; ++r) {
            #pragma unroll
            for (int cg = 0; cg < 4; ++cg)
                op0[(4 * g + r) * DMODEL + cg * 16 + q16] = oc0[cg][r] * rs[r];
        }
        if (has2) {
            ps1 += __shfl_xor(ps1, 16);
            ps1 += __shfl_xor(ps1, 32);
            const float myrs1 = qb1 ? __builtin_amdgcn_rcpf(ps1) : 0.0f;
            #pragma unroll
            for (int r = 0; r < 4; ++r) rs[r] = __shfl(myrs1, 4 * g + r);
            float* op1 = outh + (size_t)(qt1 * 16) * DMODEL;
            #pragma unroll
            for (int r = 0; r < 4; ++r) {
                #pragma unroll
                for (int cg = 0; cg < 4; ++cg)
                    op1[(4 * g + r) * DMODEL + cg * 16 + q16] = oc1[cg][r] * rs[r];
            }
        }
    }
}

__global__ __launch_bounds__(1024, 4)
void attn_fused(const float* __restrict__ R, const float* __restrict__ Rmas,
                const float* __restrict__ Wq, const float* __restrict__ bq,
                const float* __restrict__ Wk, const float* __restrict__ bk,
                const float* __restrict__ Wv, const float* __restrict__ bv,
                float* __restrict__ out)
{
    extern __shared__ char smem[];
    const int tid  = threadIdx.x;
    const int lane = tid & 63;
    const int wv   = tid >> 6;      // 0..15
    const int g    = lane >> 4;
    const int q16  = lane & 15;
    const int csw  = (q16 & 7) << 4;

    // 256 blocks: b = blk/8; block j of 8 handles 1 full head + 1 half head
    const int blk = blockIdx.x;
    const int b   = blk >> 3;
    const int j   = blk & 7;
    int h_full, h_half, qlo2, qhi2;
    if (j & 1) { h_half = (3 * j - 1) >> 1; qlo2 = 13; qhi2 = 25; h_full = (3 * j + 1) >> 1; }
    else       { h_full = (3 * j) >> 1;     h_half = h_full + 1; qlo2 = 0;  qhi2 = 13; }

    // ---------- phase 0: stage W, bias, mask bits, penalty table; zero-pad VT ----------
    {
        if (tid < 768) {
            const int m   = tid >> 8;
            const int idx = tid & 255;
            const int row = idx >> 2;          // 0..63
            const int c0  = (idx & 3) << 4;    // 0,16,32,48
            const float* Wm = (m == 0 ? Wq : (m == 1 ? Wk : Wv)) + row * 64 + c0;
            const int sw = (row & 7) << 4;
            #pragma unroll
            for (int k2 = 0; k2 < 2; ++k2) {
                f32x4 v0 = *(const f32x4*)(Wm + 8 * k2);
                f32x4 v1 = *(const f32x4*)(Wm + 8 * k2 + 4);
                union { f16x2 h2[4]; f16x8 v; } hv;
                hv.h2[0] = PKRTZ(v0[0], v0[1]);
                hv.h2[1] = PKRTZ(v0[2], v0[3]);
                hv.h2[2] = PKRTZ(v1[0], v1[1]);
                hv.h2[3] = PKRTZ(v1[2], v1[3]);
                *(f16x8*)(smem + W_OFF + m * 8192 + row * 128 + ((c0 * 2 + 16 * k2) ^ sw)) = hv.v;
            }
        } else if (tid < 960) {
            const int jj = tid - 768;
            const float* bms[3] = {bq, bk, bv};
            *(float*)(smem + BIAS_OFF + jj * 4) = bms[jj >> 6][jj & 63];
        }
        if (wv < 7) {
            const int i = (wv << 6) | lane;
            const float mval = (i < NQ) ? Rmas[b * NQ + i] : 0.0f;
            unsigned long long bb = __ballot(mval != 0.0f);
            if (lane == 0) {
                ((unsigned*)(smem + MKB_OFF))[2 * wv]     = (unsigned)bb;
                ((unsigned*)(smem + MKB_OFF))[2 * wv + 1] = (unsigned)(bb >> 32);
            }
        }
        // penalty table straight from Rmas
        if (tid >= 512 && tid < 912) {
            const int k = tid - 512;
            *(float*)(smem + PEN_OFF + k * 4) =
                (Rmas[b * NQ + k] != 0.0f) ? -M0 : -(M0 + PEN);
        }
        if (tid < 256) {
            const int r = tid >> 2, c = tid & 3;
            *(f16x4*)(smem + VT_OFF + r * 848 + 768 + c * 16 + 8) = (f16x4){0, 0, 0, 0};
        }
    }
    __syncthreads();

    const float* Rb = R + (size_t)b * NQ * DMODEL;
    float* outb = out + (size_t)b * NQ * DMODEL;

    // segment A: full head
    run_seg(smem, Rb + h_full * 64, outb + h_full * 64, 0, 25, wv, g, q16, csw);
    __syncthreads();   // drain segA phase-2 LDS reads before segB overwrites K/VT
    // segment B: half head
    run_seg(smem, Rb + h_half * 64, outb + h_half * 64, qlo2, qhi2, wv, g, q16, csw);
}

extern "C" void kernel_launch(void* const* d_in, const int* in_sizes, int n_in,
                              void* d_out, int out_size, void* d_ws, size_t ws_size,
                              hipStream_t stream) {
    const float* R    = (const float*)d_in[0];
    const float* Rmas = (const float*)d_in[1];
    const float* Wq   = (const float*)d_in[2];
    const float* bq   = (const float*)d_in[3];
    const float* Wk   = (const float*)d_in[4];
    const float* bk   = (const float*)d_in[5];
    const float* Wv   = (const float*)d_in[6];
    const float* bv   = (const float*)d_in[7];
    float* out = (float*)d_out;

    (void)hipFuncSetAttribute(reinterpret_cast<const void*>(attn_fused),
                              hipFuncAttributeMaxDynamicSharedMemorySize, SMEM_BYTES);
    attn_fused<<<dim3(256), dim3(1024), SMEM_BYTES, stream>>>(R, Rmas, Wq, bq, Wk, bk, Wv, bv, out);
}

// Round 18
// 42.886 us; speedup vs baseline: 1.1777x; 1.1777x over previous
//
#include <hip/hip_runtime.h>

typedef float    f32x4 __attribute__((ext_vector_type(4)));
typedef _Float16 f16x8 __attribute__((ext_vector_type(8)));
typedef _Float16 f16x4 __attribute__((ext_vector_type(4)));
typedef _Float16 f16x2 __attribute__((ext_vector_type(2)));
typedef __fp16   fp16x2_raw __attribute__((ext_vector_type(2)));

#define MFMA16 __builtin_amdgcn_mfma_f32_16x16x32_f16

__device__ __forceinline__ f16x2 pkrtz(float a, float b) {
    fp16x2_raw t = __builtin_amdgcn_cvt_pkrtz(a, b);
    union { fp16x2_raw r; f16x2 h; } u;
    u.r = t;
    return u.h;
}
#define PKRTZ pkrtz

#define NQ     400
#define DMODEL 768

// streaming softmax, fixed offset: p = 2^(fma(S, SCL, pen[k]))
#define SCL 0.18033688011112042f   /* 0.125 * log2(e) */
#define PEN 18033.688011112043f    /* 12500 * log2(e) */
#define M0  8.0f

// LDS layout (bytes)
#define K_OFF    0                  // K fp16 [400][64perm], 128B rows, XOR-swizzled by (row&7)<<4
#define VT_OFF   51200              // V^T fp16 [64][424], 848B rows, k block-permuted; 54272B
#define W_OFF    105472             // W fp16 x3, [64] rows of 128B, XOR-swizzled; 24576B
#define PEN_OFF  130048             // f32[400] penalty table
#define BIAS_OFF 131648             // bias f32 [3][64]
#define MKB_OFF  132416             // mask bits, 16 u32
#define SMEM_BYTES 132480

__device__ __forceinline__ f16x8 cvt8(const float* rp) {
    f32x4 u0 = *(const f32x4*)(rp);
    f32x4 u1 = *(const f32x4*)(rp + 4);
    union { f16x2 h2[4]; f16x8 v; } u;
    u.h2[0] = PKRTZ(u0[0], u0[1]);
    u.h2[1] = PKRTZ(u0[2], u0[3]);
    u.h2[2] = PKRTZ(u1[0], u1[1]);
    u.h2[3] = PKRTZ(u1[2], u1[3]);
    return u.v;
}

__global__ __launch_bounds__(1024, 4)
void attn_fused(const float* __restrict__ R, const float* __restrict__ Rmas,
                const float* __restrict__ Wq, const float* __restrict__ bq,
                const float* __restrict__ Wk, const float* __restrict__ bk,
                const float* __restrict__ Wv, const float* __restrict__ bv,
                float* __restrict__ out)
{
    extern __shared__ char smem[];
    const int tid  = threadIdx.x;
    const int lane = tid & 63;
    const int wv   = tid >> 6;      // 0..15
    const int g    = lane >> 4;
    const int q16  = lane & 15;
    const int csw  = (q16 & 7) << 4;

    const int blk = blockIdx.x;
    const int b   = blk / 12;
    const int h   = blk % 12;

    // ---------- phase 0: stage W, bias, mask bits, penalty table; zero-pad VT ----------
    {
        if (tid < 768) {
            const int m   = tid >> 8;
            const int idx = tid & 255;
            const int row = idx >> 2;          // 0..63
            const int c0  = (idx & 3) << 4;    // 0,16,32,48
            const float* Wm = (m == 0 ? Wq : (m == 1 ? Wk : Wv)) + row * 64 + c0;
            const int sw = (row & 7) << 4;
            #pragma unroll
            for (int k2 = 0; k2 < 2; ++k2) {
                f32x4 v0 = *(const f32x4*)(Wm + 8 * k2);
                f32x4 v1 = *(const f32x4*)(Wm + 8 * k2 + 4);
                union { f16x2 h2[4]; f16x8 v; } hv;
                hv.h2[0] = PKRTZ(v0[0], v0[1]);
                hv.h2[1] = PKRTZ(v0[2], v0[3]);
                hv.h2[2] = PKRTZ(v1[0], v1[1]);
                hv.h2[3] = PKRTZ(v1[2], v1[3]);
                *(f16x8*)(smem + W_OFF + m * 8192 + row * 128 + ((c0 * 2 + 16 * k2) ^ sw)) = hv.v;
            }
        } else if (tid < 960) {
            const int jj = tid - 768;
            const float* bms[3] = {bq, bk, bv};
            *(float*)(smem + BIAS_OFF + jj * 4) = bms[jj >> 6][jj & 63];
        }
        if (wv < 7) {
            const int i = (wv << 6) | lane;
            const float mval = (i < NQ) ? Rmas[b * NQ + i] : 0.0f;
            unsigned long long bb = __ballot(mval != 0.0f);
            if (lane == 0) {
                ((unsigned*)(smem + MKB_OFF))[2 * wv]     = (unsigned)bb;
                ((unsigned*)(smem + MKB_OFF))[2 * wv + 1] = (unsigned)(bb >> 32);
            }
        }
        // penalty table straight from Rmas
        if (tid >= 512 && tid < 912) {
            const int k = tid - 512;
            *(float*)(smem + PEN_OFF + k * 4) =
                (Rmas[b * NQ + k] != 0.0f) ? -M0 : -(M0 + PEN);
        }
        if (tid < 256) {
            const int r = tid >> 2, c = tid & 3;
            *(f16x4*)(smem + VT_OFF + r * 848 + 768 + c * 16 + 8) = (f16x4){0, 0, 0, 0};
        }
    }
    __syncthreads();

    const float* Rbh = R + (size_t)b * NQ * DMODEL + h * 64;

    // ---------- phase 1: fused map, W-fragment reuse across the wave's two tiles ----------
    // Wave wv owns tiles {2wv, 2wv+1} for K, V AND Q. Both R-tiles are loaded and
    // converted up front; then per W-matrix x per-cg the wb pair is loaded ONCE and
    // applied to both tiles (halves phase-1 W ds_reads vs per-tile projection).
    f16x8 qreg0[2], qreg1[2];
    const int tA = 2 * wv, tB = 2 * wv + 1;
    const bool vA = (tA < 25), vB = (tB < 25);

    f16x8 afA0, afA1, afB0, afB1;
    if (vA) {
        const float* rp = Rbh + (size_t)(tA * 16 + q16) * DMODEL + g * 8;
        afA0 = cvt8(rp);
        afA1 = cvt8(rp + 32);
    }
    if (vB) {
        const float* rp = Rbh + (size_t)(tB * 16 + q16) * DMODEL + g * 8;
        afB0 = cvt8(rp);
        afB1 = cvt8(rp + 32);
    }

    // --- V projections (normal orientation: A=R-frag, B=Wv-frag) ---
    if (vA) {
        #pragma unroll
        for (int cg = 0; cg < 4; ++cg) {
            const int col = cg * 16 + q16;
            f16x8 wb0 = *(const f16x8*)(smem + W_OFF + 16384 + col * 128 + ((g * 16) ^ csw));
            f16x8 wb1 = *(const f16x8*)(smem + W_OFF + 16384 + col * 128 + ((64 + g * 16) ^ csw));
            const float bb = *(const float*)(smem + BIAS_OFF + (128 + col) * 4);
            f32x4 accA = {bb, bb, bb, bb};
            accA = MFMA16(afA0, wb0, accA, 0, 0, 0);
            accA = MFMA16(afA1, wb1, accA, 0, 0, 0);
            union { f16x2 h2[2]; f16x4 v; } hvA;
            hvA.h2[0] = PKRTZ(accA[0], accA[1]);
            hvA.h2[1] = PKRTZ(accA[2], accA[3]);
            *(f16x4*)(smem + VT_OFF + col * 848 + (tA >> 1) * 64 + g * 16 + (tA & 1) * 8) = hvA.v;
            if (vB) {
                f32x4 accB = {bb, bb, bb, bb};
                accB = MFMA16(afB0, wb0, accB, 0, 0, 0);
                accB = MFMA16(afB1, wb1, accB, 0, 0, 0);
                union { f16x2 h2[2]; f16x4 v; } hvB;
                hvB.h2[0] = PKRTZ(accB[0], accB[1]);
                hvB.h2[1] = PKRTZ(accB[2], accB[3]);
                *(f16x4*)(smem + VT_OFF + col * 848 + (tB >> 1) * 64 + g * 16 + (tB & 1) * 8) = hvB.v;
            }
        }
    }

    // --- K projections (SWAPPED: A=Wk-frag, B=R-frag) ---
    if (vA) {
        #pragma unroll
        for (int cg = 0; cg < 4; ++cg) {
            const int d0 = cg * 16 + 4 * g;
            f16x8 wb0 = *(const f16x8*)(smem + W_OFF + 8192 + (cg * 16 + q16) * 128 + ((g * 16) ^ csw));
            f16x8 wb1 = *(const f16x8*)(smem + W_OFF + 8192 + (cg * 16 + q16) * 128 + ((64 + g * 16) ^ csw));
            const f32x4 bv4 = *(const f32x4*)(smem + BIAS_OFF + (64 + d0) * 4);
            const int pos2 = ((cg & 2) << 5) + g * 16 + (cg & 1) * 8;
            f32x4 accA = bv4;
            accA = MFMA16(wb0, afA0, accA, 0, 0, 0);
            accA = MFMA16(wb1, afA1, accA, 0, 0, 0);
            union { f16x2 h2[2]; f16x4 v; } hvA;
            hvA.h2[0] = PKRTZ(accA[0], accA[1]);
            hvA.h2[1] = PKRTZ(accA[2], accA[3]);
            *(f16x4*)(smem + K_OFF + (tA * 16 + q16) * 128 + (pos2 ^ csw)) = hvA.v;
            if (vB) {
                f32x4 accB = bv4;
                accB = MFMA16(wb0, afB0, accB, 0, 0, 0);
                accB = MFMA16(wb1, afB1, accB, 0, 0, 0);
                union { f16x2 h2[2]; f16x4 v; } hvB;
                hvB.h2[0] = PKRTZ(accB[0], accB[1]);
                hvB.h2[1] = PKRTZ(accB[2], accB[3]);
                *(f16x4*)(smem + K_OFF + (tB * 16 + q16) * 128 + (pos2 ^ csw)) = hvB.v;
            }
        }
    }

    // --- Q projections (SWAPPED, to registers, packed incrementally per cg) ---
    if (vA) {
        union { f16x2 h2[4]; f16x8 v; } uA0, uA1, uB0, uB1;
        #pragma unroll
        for (int cg = 0; cg < 4; ++cg) {
            const int d0 = cg * 16 + 4 * g;
            f16x8 wb0 = *(const f16x8*)(smem + W_OFF + (cg * 16 + q16) * 128 + ((g * 16) ^ csw));
            f16x8 wb1 = *(const f16x8*)(smem + W_OFF + (cg * 16 + q16) * 128 + ((64 + g * 16) ^ csw));
            const f32x4 bv4 = *(const f32x4*)(smem + BIAS_OFF + d0 * 4);
            f32x4 accA = bv4;
            accA = MFMA16(wb0, afA0, accA, 0, 0, 0);
            accA = MFMA16(wb1, afA1, accA, 0, 0, 0);
            if (cg < 2) {
                uA0.h2[(cg & 1) * 2]     = PKRTZ(accA[0], accA[1]);
                uA0.h2[(cg & 1) * 2 + 1] = PKRTZ(accA[2], accA[3]);
            } else {
                uA1.h2[(cg & 1) * 2]     = PKRTZ(accA[0], accA[1]);
                uA1.h2[(cg & 1) * 2 + 1] = PKRTZ(accA[2], accA[3]);
            }
            if (vB) {
                f32x4 accB = bv4;
                accB = MFMA16(wb0, afB0, accB, 0, 0, 0);
                accB = MFMA16(wb1, afB1, accB, 0, 0, 0);
                if (cg < 2) {
                    uB0.h2[(cg & 1) * 2]     = PKRTZ(accB[0], accB[1]);
                    uB0.h2[(cg & 1) * 2 + 1] = PKRTZ(accB[2], accB[3]);
                } else {
                    uB1.h2[(cg & 1) * 2]     = PKRTZ(accB[0], accB[1]);
                    uB1.h2[(cg & 1) * 2 + 1] = PKRTZ(accB[2], accB[3]);
                }
            }
        }
        qreg0[0] = uA0.v;
        qreg0[1] = uA1.v;
        if (vB) { qreg1[0] = uB0.v; qreg1[1] = uB1.v; }
    }
    __syncthreads();

    // ---------- phase 2: dual-q-tile streaming attention (identical to round 16) ----------
    const int qt0 = vA ? tA : -1;
    const int qt1 = vB ? tB : -1;
    if (qt0 >= 0) {
        const bool has2 = (qt1 >= 0);
        const int qrow0 = qt0 * 16 + q16;
        const unsigned qb0 = (((const unsigned*)(smem + MKB_OFF))[qrow0 >> 5] >> (qrow0 & 31)) & 1u;
        const int qrow1 = (has2 ? qt1 : qt0) * 16 + q16;
        const unsigned qb1 = (((const unsigned*)(smem + MKB_OFF))[qrow1 >> 5] >> (qrow1 & 31)) & 1u;

        const int kbase = K_OFF + q16 * 128;
        const int o0 = (g * 16) ^ csw;
        const int o1 = (64 + g * 16) ^ csw;

        f32x4 oc0[4], oc1[4];
        #pragma unroll
        for (int cg = 0; cg < 4; ++cg) {
            oc0[cg] = (f32x4){0.f, 0.f, 0.f, 0.f};
            oc1[cg] = (f32x4){0.f, 0.f, 0.f, 0.f};
        }
        float ps0 = 0.f, ps1 = 0.f;

        // prefetch chunk 0, both tiles
        f16x8 ka0 = *(const f16x8*)(smem + kbase + o0);
        f16x8 ka1 = *(const f16x8*)(smem + kbase + o1);
        f16x8 kb0 = *(const f16x8*)(smem + kbase + 2048 + o0);
        f16x8 kb1 = *(const f16x8*)(smem + kbase + 2048 + o1);

        #pragma unroll 1
        for (int kc = 0; kc < 12; ++kc) {
            f32x4 pa4 = *(const f32x4*)(smem + PEN_OFF + (kc * 32 + 4 * g) * 4);
            f32x4 pb4 = *(const f32x4*)(smem + PEN_OFF + (kc * 32 + 16 + 4 * g) * 4);

            __builtin_amdgcn_s_setprio(1);
            f32x4 accA0 = {0.f, 0.f, 0.f, 0.f};
            accA0 = MFMA16(ka0, qreg0[0], accA0, 0, 0, 0);
            accA0 = MFMA16(ka1, qreg0[1], accA0, 0, 0, 0);
            f32x4 accB0 = {0.f, 0.f, 0.f, 0.f};
            accB0 = MFMA16(kb0, qreg0[0], accB0, 0, 0, 0);
            accB0 = MFMA16(kb1, qreg0[1], accB0, 0, 0, 0);
            f32x4 accA1 = {0.f, 0.f, 0.f, 0.f};
            f32x4 accB1 = {0.f, 0.f, 0.f, 0.f};
            if (has2) {
                accA1 = MFMA16(ka0, qreg1[0], accA1, 0, 0, 0);
                accA1 = MFMA16(ka1, qreg1[1], accA1, 0, 0, 0);
                accB1 = MFMA16(kb0, qreg1[0], accB1, 0, 0, 0);
                accB1 = MFMA16(kb1, qreg1[1], accB1, 0, 0, 0);
            }
            __builtin_amdgcn_s_setprio(0);

            // prefetch next chunk (kc=11: tileA = tail rows 384..399; tileB lands in VT, unused)
            const char* kn = smem + kbase + (kc + 1) * 4096;
            ka0 = *(const f16x8*)(kn + o0);
            ka1 = *(const f16x8*)(kn + o1);
            kb0 = *(const f16x8*)(kn + 2048 + o0);
            kb1 = *(const f16x8*)(kn + 2048 + o1);

            const float e0 = __builtin_amdgcn_exp2f(fmaf(accA0[0], SCL, pa4[0]));
            const float e1 = __builtin_amdgcn_exp2f(fmaf(accA0[1], SCL, pa4[1]));
            const float e2 = __builtin_amdgcn_exp2f(fmaf(accA0[2], SCL, pa4[2]));
            const float e3 = __builtin_amdgcn_exp2f(fmaf(accA0[3], SCL, pa4[3]));
            const float e4 = __builtin_amdgcn_exp2f(fmaf(accB0[0], SCL, pb4[0]));
            const float e5 = __builtin_amdgcn_exp2f(fmaf(accB0[1], SCL, pb4[1]));
            const float e6 = __builtin_amdgcn_exp2f(fmaf(accB0[2], SCL, pb4[2]));
            const float e7 = __builtin_amdgcn_exp2f(fmaf(accB0[3], SCL, pb4[3]));
            ps0 += ((e0 + e1) + (e2 + e3)) + ((e4 + e5) + (e6 + e7));
            union { f16x2 h2[4]; f16x8 v; } pu0;
            pu0.h2[0] = PKRTZ(e0, e1);
            pu0.h2[1] = PKRTZ(e2, e3);
            pu0.h2[2] = PKRTZ(e4, e5);
            pu0.h2[3] = PKRTZ(e6, e7);
            const f16x8 pfrag0 = pu0.v;

            f16x8 pfrag1;
            if (has2) {
                const float f0 = __builtin_amdgcn_exp2f(fmaf(accA1[0], SCL, pa4[0]));
                const float f1 = __builtin_amdgcn_exp2f(fmaf(accA1[1], SCL, pa4[1]));
                const float f2 = __builtin_amdgcn_exp2f(fmaf(accA1[2], SCL, pa4[2]));
                const float f3 = __builtin_amdgcn_exp2f(fmaf(accA1[3], SCL, pa4[3]));
                const float f4 = __builtin_amdgcn_exp2f(fmaf(accB1[0], SCL, pb4[0]));
                const float f5 = __builtin_amdgcn_exp2f(fmaf(accB1[1], SCL, pb4[1]));
                const float f6 = __builtin_amdgcn_exp2f(fmaf(accB1[2], SCL, pb4[2]));
                const float f7 = __builtin_amdgcn_exp2f(fmaf(accB1[3], SCL, pb4[3]));
                ps1 += ((f0 + f1) + (f2 + f3)) + ((f4 + f5) + (f6 + f7));
                union { f16x2 h2[4]; f16x8 v; } pu1;
                pu1.h2[0] = PKRTZ(f0, f1);
                pu1.h2[1] = PKRTZ(f2, f3);
                pu1.h2[2] = PKRTZ(f4, f5);
                pu1.h2[3] = PKRTZ(f6, f7);
                pfrag1 = pu1.v;
            }

            __builtin_amdgcn_s_setprio(1);
            #pragma unroll
            for (int cg = 0; cg < 4; ++cg) {
                f16x8 vb = *(const f16x8*)(smem + VT_OFF + (cg * 16 + q16) * 848 + kc * 64 + g * 16);
                oc0[cg] = MFMA16(pfrag0, vb, oc0[cg], 0, 0, 0);
                if (has2) oc1[cg] = MFMA16(pfrag1, vb, oc1[cg], 0, 0, 0);
            }
            __builtin_amdgcn_s_setprio(0);
        }
        // tail: tile 24 (keys 384..399) via last prefetch; upper half zero pad
        {
            f32x4 pa4 = *(const f32x4*)(smem + PEN_OFF + (384 + 4 * g) * 4);
            f32x4 accA0 = {0.f, 0.f, 0.f, 0.f};
            accA0 = MFMA16(ka0, qreg0[0], accA0, 0, 0, 0);
            accA0 = MFMA16(ka1, qreg0[1], accA0, 0, 0, 0);
            const float e0 = __builtin_amdgcn_exp2f(fmaf(accA0[0], SCL, pa4[0]));
            const float e1 = __builtin_amdgcn_exp2f(fmaf(accA0[1], SCL, pa4[1]));
            const float e2 = __builtin_amdgcn_exp2f(fmaf(accA0[2], SCL, pa4[2]));
            const float e3 = __builtin_amdgcn_exp2f(fmaf(accA0[3], SCL, pa4[3]));
            ps0 += (e0 + e1) + (e2 + e3);
            union { f16x2 h2[4]; f16x8 v; } pu0;
            pu0.h2[0] = PKRTZ(e0, e1);
            pu0.h2[1] = PKRTZ(e2, e3);
            pu0.h2[2] = (f16x2){0, 0};
            pu0.h2[3] = (f16x2){0, 0};
            const f16x8 pfrag0 = pu0.v;

            f16x8 pfrag1;
            if (has2) {
                f32x4 accA1 = {0.f, 0.f, 0.f, 0.f};
                accA1 = MFMA16(ka0, qreg1[0], accA1, 0, 0, 0);
                accA1 = MFMA16(ka1, qreg1[1], accA1, 0, 0, 0);
                const float f0 = __builtin_amdgcn_exp2f(fmaf(accA1[0], SCL, pa4[0]));
                const float f1 = __builtin_amdgcn_exp2f(fmaf(accA1[1], SCL, pa4[1]));
                const float f2 = __builtin_amdgcn_exp2f(fmaf(accA1[2], SCL, pa4[2]));
                const float f3 = __builtin_amdgcn_exp2f(fmaf(accA1[3], SCL, pa4[3]));
                ps1 += (f0 + f1) + (f2 + f3);
                union { f16x2 h2[4]; f16x8 v; } pu1;
                pu1.h2[0] = PKRTZ(f0, f1);
                pu1.h2[1] = PKRTZ(f2, f3);
                pu1.h2[2] = (f16x2){0, 0};
                pu1.h2[3] = (f16x2){0, 0};
                pfrag1 = pu1.v;
            }
            #pragma unroll
            for (int cg = 0; cg < 4; ++cg) {
                f16x8 vb = *(const f16x8*)(smem + VT_OFF + (cg * 16 + q16) * 848 + 12 * 64 + g * 16);
                oc0[cg] = MFMA16(pfrag0, vb, oc0[cg], 0, 0, 0);
                if (has2) oc1[cg] = MFMA16(pfrag1, vb, oc1[cg], 0, 0, 0);
            }
        }

        // row sums + epilogues
        ps0 += __shfl_xor(ps0, 16);
        ps0 += __shfl_xor(ps0, 32);
        const float myrs0 = qb0 ? __builtin_amdgcn_rcpf(ps0) : 0.0f;
        float rs[4];
        #pragma unroll
        for (int r = 0; r < 4; ++r) rs[r] = __shfl(myrs0, 4 * g + r);
        float* op0 = out + (size_t)(b * NQ + qt0 * 16) * DMODEL + h * 64;
        #pragma unroll
        for (int r = 0; r < 4; ++r) {
            #pragma unroll
            for (int cg = 0; cg < 4; ++cg)
                op0[(4 * g + r) * DMODEL + cg * 16 + q16] = oc0[cg][r] * rs[r];
        }
        if (has2) {
            ps1 += __shfl_xor(ps1, 16);
            ps1 += __shfl_xor(ps1, 32);
            const float myrs1 = qb1 ? __builtin_amdgcn_rcpf(ps1) : 0.0f;
            #pragma unroll
            for (int r = 0; r < 4; ++r) rs[r] = __shfl(myrs1, 4 * g + r);
            float* op1 = out + (size_t)(b * NQ + qt1 * 16) * DMODEL + h * 64;
            #pragma unroll
            for (int r = 0; r < 4; ++r) {
                #pragma unroll
                for (int cg = 0; cg < 4; ++cg)
                    op1[(4 * g + r) * DMODEL + cg * 16 + q16] = oc1[cg][r] * rs[r];
            }
        }
    }
}

extern "C" void kernel_launch(void* const* d_in, const int* in_sizes, int n_in,
                              void* d_out, int out_size, void* d_ws, size_t ws_size,
                              hipStream_t stream) {
    const float* R    = (const float*)d_in[0];
    const float* Rmas = (const float*)d_in[1];
    const float* Wq   = (const float*)d_in[2];
    const float* bq   = (const float*)d_in[3];
    const float* Wk   = (const float*)d_in[4];
    const float* bk   = (const float*)d_in[5];
    const float* Wv   = (const float*)d_in[6];
    const float* bv   = (const float*)d_in[7];
    float* out = (float*)d_out;

    (void)hipFuncSetAttribute(reinterpret_cast<const void*>(attn_fused),
                              hipFuncAttributeMaxDynamicSharedMemorySize, SMEM_BYTES);
    attn_fused<<<dim3(384), dim3(1024), SMEM_BYTES, stream>>>(R, Rmas, Wq, bq, Wk, bk, Wv, bv, out);
}

// Round 19
// 40.681 us; speedup vs baseline: 1.2416x; 1.0542x over previous
//
#include <hip/hip_runtime.h>

typedef float    f32x4 __attribute__((ext_vector_type(4)));
typedef _Float16 f16x8 __attribute__((ext_vector_type(8)));
typedef _Float16 f16x4 __attribute__((ext_vector_type(4)));
typedef _Float16 f16x2 __attribute__((ext_vector_type(2)));
typedef __fp16   fp16x2_raw __attribute__((ext_vector_type(2)));

#define MFMA16 __builtin_amdgcn_mfma_f32_16x16x32_f16

__device__ __forceinline__ f16x2 pkrtz(float a, float b) {
    fp16x2_raw t = __builtin_amdgcn_cvt_pkrtz(a, b);
    union { fp16x2_raw r; f16x2 h; } u;
    u.r = t;
    return u.h;
}
#define PKRTZ pkrtz

#define NQ     400
#define DMODEL 768

// streaming softmax, fixed offset: p = 2^(fma(S, SCL, pen[k]))
#define SCL 0.18033688011112042f   /* 0.125 * log2(e) */
#define PEN 18033.688011112043f    /* 12500 * log2(e) */
#define M0  8.0f

// LDS layout (bytes)
#define K_OFF    0                  // K fp16 [400][64perm], 128B rows, XOR-swizzled by (row&7)<<4
#define VT_OFF   51200              // V^T fp16 [64][424], 848B rows, k block-permuted; 54272B
#define W_OFF    105472             // W fp16 x3, [64] rows of 128B, XOR-swizzled; 24576B
#define PEN_OFF  130048             // f32[400] penalty table
#define BIAS_OFF 131648             // bias f32 [3][64]
#define MKB_OFF  132416             // mask bits, 16 u32
#define SMEM_BYTES 132480

__device__ __forceinline__ f16x8 cvt8(const float* rp) {
    f32x4 u0 = *(const f32x4*)(rp);
    f32x4 u1 = *(const f32x4*)(rp + 4);
    union { f16x2 h2[4]; f16x8 v; } u;
    u.h2[0] = PKRTZ(u0[0], u0[1]);
    u.h2[1] = PKRTZ(u0[2], u0[3]);
    u.h2[2] = PKRTZ(u1[0], u1[1]);
    u.h2[3] = PKRTZ(u1[2], u1[3]);
    return u.v;
}

// V projection (A=R-frag, B=Wv-frag) -> VT rows, b64 writes
__device__ __forceinline__ void proj_v(char* smem, f16x8 af0, f16x8 af1,
                                       int t, int g, int q16, int csw) {
    #pragma unroll
    for (int cg = 0; cg < 4; ++cg) {
        const int col = cg * 16 + q16;
        const float bb = *(const float*)(smem + BIAS_OFF + (128 + col) * 4);
        f32x4 acc = {bb, bb, bb, bb};
        f16x8 wb0 = *(const f16x8*)(smem + W_OFF + 16384 + col * 128 + ((g * 16) ^ csw));
        f16x8 wb1 = *(const f16x8*)(smem + W_OFF + 16384 + col * 128 + ((64 + g * 16) ^ csw));
        acc = MFMA16(af0, wb0, acc, 0, 0, 0);
        acc = MFMA16(af1, wb1, acc, 0, 0, 0);
        union { f16x2 h2[2]; f16x4 v; } hv;
        hv.h2[0] = PKRTZ(acc[0], acc[1]);
        hv.h2[1] = PKRTZ(acc[2], acc[3]);
        *(f16x4*)(smem + VT_OFF + col * 848 + (t >> 1) * 64 + g * 16 + (t & 1) * 8) = hv.v;
    }
}

// K projection (SWAPPED: A=Wk-frag, B=R-frag) -> K row kk, permuted cols, b64 writes
__device__ __forceinline__ void proj_k(char* smem, f16x8 af0, f16x8 af1,
                                       int kk, int g, int q16, int csw) {
    #pragma unroll
    for (int cg = 0; cg < 4; ++cg) {
        const int d0 = cg * 16 + 4 * g;
        f32x4 acc = *(const f32x4*)(smem + BIAS_OFF + (64 + d0) * 4);
        f16x8 wb0 = *(const f16x8*)(smem + W_OFF + 8192 + (cg * 16 + q16) * 128 + ((g * 16) ^ csw));
        f16x8 wb1 = *(const f16x8*)(smem + W_OFF + 8192 + (cg * 16 + q16) * 128 + ((64 + g * 16) ^ csw));
        acc = MFMA16(wb0, af0, acc, 0, 0, 0);   // C[d][q]
        acc = MFMA16(wb1, af1, acc, 0, 0, 0);
        union { f16x2 h2[2]; f16x4 v; } hv;
        hv.h2[0] = PKRTZ(acc[0], acc[1]);
        hv.h2[1] = PKRTZ(acc[2], acc[3]);
        const int pos2 = ((cg & 2) << 5) + g * 16 + (cg & 1) * 8;
        *(f16x4*)(smem + K_OFF + kk * 128 + (pos2 ^ csw)) = hv.v;
    }
}

// Q projection (SWAPPED) -> register B-fragments, permuted k-order
__device__ __forceinline__ void proj_q(char* smem, f16x8 af0, f16x8 af1,
                                       int g, int q16, int csw, f16x8 (&qreg)[2]) {
    f32x4 qa[4];
    #pragma unroll
    for (int cg = 0; cg < 4; ++cg) {
        const int d0 = cg * 16 + 4 * g;
        f32x4 acc = *(const f32x4*)(smem + BIAS_OFF + d0 * 4);
        f16x8 wb0 = *(const f16x8*)(smem + W_OFF + (cg * 16 + q16) * 128 + ((g * 16) ^ csw));
        f16x8 wb1 = *(const f16x8*)(smem + W_OFF + (cg * 16 + q16) * 128 + ((64 + g * 16) ^ csw));
        acc = MFMA16(wb0, af0, acc, 0, 0, 0);
        acc = MFMA16(wb1, af1, acc, 0, 0, 0);
        qa[cg] = acc;
    }
    union { f16x2 h2[4]; f16x8 v; } u0, u1;
    u0.h2[0] = PKRTZ(qa[0][0], qa[0][1]);
    u0.h2[1] = PKRTZ(qa[0][2], qa[0][3]);
    u0.h2[2] = PKRTZ(qa[1][0], qa[1][1]);
    u0.h2[3] = PKRTZ(qa[1][2], qa[1][3]);
    u1.h2[0] = PKRTZ(qa[2][0], qa[2][1]);
    u1.h2[1] = PKRTZ(qa[2][2], qa[2][3]);
    u1.h2[2] = PKRTZ(qa[3][0], qa[3][1]);
    u1.h2[3] = PKRTZ(qa[3][2], qa[3][3]);
    qreg[0] = u0.v;
    qreg[1] = u1.v;
}

__global__ __launch_bounds__(1024, 4)
void attn_fused(const float* __restrict__ R, const float* __restrict__ Rmas,
                const float* __restrict__ Wq, const float* __restrict__ bq,
                const float* __restrict__ Wk, const float* __restrict__ bk,
                const float* __restrict__ Wv, const float* __restrict__ bv,
                float* __restrict__ out)
{
    extern __shared__ char smem[];
    const int tid  = threadIdx.x;
    const int lane = tid & 63;
    const int wv   = tid >> 6;      // 0..15
    const int g    = lane >> 4;
    const int q16  = lane & 15;
    const int csw  = (q16 & 7) << 4;

    const int blk = blockIdx.x;
    const int b   = blk / 12;
    const int h   = blk % 12;

    // ---------- phase 0: stage W, bias, mask bits, penalty table; zero-pad VT ----------
    {
        if (tid < 768) {
            const int m   = tid >> 8;
            const int idx = tid & 255;
            const int row = idx >> 2;          // 0..63
            const int c0  = (idx & 3) << 4;    // 0,16,32,48
            const float* Wm = (m == 0 ? Wq : (m == 1 ? Wk : Wv)) + row * 64 + c0;
            const int sw = (row & 7) << 4;
            #pragma unroll
            for (int k2 = 0; k2 < 2; ++k2) {
                f32x4 v0 = *(const f32x4*)(Wm + 8 * k2);
                f32x4 v1 = *(const f32x4*)(Wm + 8 * k2 + 4);
                union { f16x2 h2[4]; f16x8 v; } hv;
                hv.h2[0] = PKRTZ(v0[0], v0[1]);
                hv.h2[1] = PKRTZ(v0[2], v0[3]);
                hv.h2[2] = PKRTZ(v1[0], v1[1]);
                hv.h2[3] = PKRTZ(v1[2], v1[3]);
                *(f16x8*)(smem + W_OFF + m * 8192 + row * 128 + ((c0 * 2 + 16 * k2) ^ sw)) = hv.v;
            }
        } else if (tid < 960) {
            const int jj = tid - 768;
            const float* bms[3] = {bq, bk, bv};
            *(float*)(smem + BIAS_OFF + jj * 4) = bms[jj >> 6][jj & 63];
        }
        if (wv < 7) {
            const int i = (wv << 6) | lane;
            const float mval = (i < NQ) ? Rmas[b * NQ + i] : 0.0f;
            unsigned long long bb = __ballot(mval != 0.0f);
            if (lane == 0) {
                ((unsigned*)(smem + MKB_OFF))[2 * wv]     = (unsigned)bb;
                ((unsigned*)(smem + MKB_OFF))[2 * wv + 1] = (unsigned)(bb >> 32);
            }
        }
        // penalty table straight from Rmas
        if (tid >= 512 && tid < 912) {
            const int k = tid - 512;
            *(float*)(smem + PEN_OFF + k * 4) =
                (Rmas[b * NQ + k] != 0.0f) ? -M0 : -(M0 + PEN);
        }
        if (tid < 256) {
            const int r = tid >> 2, c = tid & 3;
            *(f16x4*)(smem + VT_OFF + r * 848 + 768 + c * 16 + 8) = (f16x4){0, 0, 0, 0};
        }
    }
    __syncthreads();

    const float* Rbh = R + (size_t)b * NQ * DMODEL + h * 64;

    // ---------- phase 1: fused map (round 16) — wave wv owns tiles {2wv, 2wv+1}
    //            for K, V AND Q; one R-tile load feeds all three projections ----------
    f16x8 qreg0[2], qreg1[2];
    const int qt0 = (2 * wv < 25)     ? (2 * wv)     : -1;
    const int qt1 = (2 * wv + 1 < 25) ? (2 * wv + 1) : -1;
    if (qt0 >= 0) {
        const float* rp = Rbh + (size_t)(qt0 * 16 + q16) * DMODEL + g * 8;
        f16x8 af0 = cvt8(rp);
        f16x8 af1 = cvt8(rp + 32);
        proj_k(smem, af0, af1, qt0 * 16 + q16, g, q16, csw);
        proj_v(smem, af0, af1, qt0, g, q16, csw);
        proj_q(smem, af0, af1, g, q16, csw, qreg0);
    }
    if (qt1 >= 0) {
        const float* rp = Rbh + (size_t)(qt1 * 16 + q16) * DMODEL + g * 8;
        f16x8 af0 = cvt8(rp);
        f16x8 af1 = cvt8(rp + 32);
        proj_k(smem, af0, af1, qt1 * 16 + q16, g, q16, csw);
        proj_v(smem, af0, af1, qt1, g, q16, csw);
        proj_q(smem, af0, af1, g, q16, csw, qreg1);
    }
    __syncthreads();

    // ---------- phase 2: dual-q-tile streaming attention; ps via ones-MFMA ----------
    if (qt0 >= 0) {
        const bool has2 = (qt1 >= 0);

        const int kbase = K_OFF + q16 * 128;
        const int o0 = (g * 16) ^ csw;
        const int o1 = (64 + g * 16) ^ csw;

        const f16x8 ones = {(_Float16)1.f, (_Float16)1.f, (_Float16)1.f, (_Float16)1.f,
                            (_Float16)1.f, (_Float16)1.f, (_Float16)1.f, (_Float16)1.f};

        f32x4 oc0[4], oc1[4];
        #pragma unroll
        for (int cg = 0; cg < 4; ++cg) {
            oc0[cg] = (f32x4){0.f, 0.f, 0.f, 0.f};
            oc1[cg] = (f32x4){0.f, 0.f, 0.f, 0.f};
        }
        f32x4 psacc0 = {0.f, 0.f, 0.f, 0.f};
        f32x4 psacc1 = {0.f, 0.f, 0.f, 0.f};

        // prefetch chunk 0, both tiles
        f16x8 ka0 = *(const f16x8*)(smem + kbase + o0);
        f16x8 ka1 = *(const f16x8*)(smem + kbase + o1);
        f16x8 kb0 = *(const f16x8*)(smem + kbase + 2048 + o0);
        f16x8 kb1 = *(const f16x8*)(smem + kbase + 2048 + o1);

        #pragma unroll 1
        for (int kc = 0; kc < 12; ++kc) {
            f32x4 pa4 = *(const f32x4*)(smem + PEN_OFF + (kc * 32 + 4 * g) * 4);
            f32x4 pb4 = *(const f32x4*)(smem + PEN_OFF + (kc * 32 + 16 + 4 * g) * 4);

            __builtin_amdgcn_s_setprio(1);
            f32x4 accA0 = {0.f, 0.f, 0.f, 0.f};
            accA0 = MFMA16(ka0, qreg0[0], accA0, 0, 0, 0);
            accA0 = MFMA16(ka1, qreg0[1], accA0, 0, 0, 0);
            f32x4 accB0 = {0.f, 0.f, 0.f, 0.f};
            accB0 = MFMA16(kb0, qreg0[0], accB0, 0, 0, 0);
            accB0 = MFMA16(kb1, qreg0[1], accB0, 0, 0, 0);
            f32x4 accA1 = {0.f, 0.f, 0.f, 0.f};
            f32x4 accB1 = {0.f, 0.f, 0.f, 0.f};
            if (has2) {
                accA1 = MFMA16(ka0, qreg1[0], accA1, 0, 0, 0);
                accA1 = MFMA16(ka1, qreg1[1], accA1, 0, 0, 0);
                accB1 = MFMA16(kb0, qreg1[0], accB1, 0, 0, 0);
                accB1 = MFMA16(kb1, qreg1[1], accB1, 0, 0, 0);
            }
            __builtin_amdgcn_s_setprio(0);

            // prefetch next chunk (kc=11: tileA = tail rows 384..399; tileB lands in VT, unused)
            const char* kn = smem + kbase + (kc + 1) * 4096;
            ka0 = *(const f16x8*)(kn + o0);
            ka1 = *(const f16x8*)(kn + o1);
            kb0 = *(const f16x8*)(kn + 2048 + o0);
            kb1 = *(const f16x8*)(kn + 2048 + o1);

            const float e0 = __builtin_amdgcn_exp2f(fmaf(accA0[0], SCL, pa4[0]));
            const float e1 = __builtin_amdgcn_exp2f(fmaf(accA0[1], SCL, pa4[1]));
            const float e2 = __builtin_amdgcn_exp2f(fmaf(accA0[2], SCL, pa4[2]));
            const float e3 = __builtin_amdgcn_exp2f(fmaf(accA0[3], SCL, pa4[3]));
            const float e4 = __builtin_amdgcn_exp2f(fmaf(accB0[0], SCL, pb4[0]));
            const float e5 = __builtin_amdgcn_exp2f(fmaf(accB0[1], SCL, pb4[1]));
            const float e6 = __builtin_amdgcn_exp2f(fmaf(accB0[2], SCL, pb4[2]));
            const float e7 = __builtin_amdgcn_exp2f(fmaf(accB0[3], SCL, pb4[3]));
            union { f16x2 h2[4]; f16x8 v; } pu0;
            pu0.h2[0] = PKRTZ(e0, e1);
            pu0.h2[1] = PKRTZ(e2, e3);
            pu0.h2[2] = PKRTZ(e4, e5);
            pu0.h2[3] = PKRTZ(e6, e7);
            const f16x8 pfrag0 = pu0.v;

            f16x8 pfrag1;
            if (has2) {
                const float f0 = __builtin_amdgcn_exp2f(fmaf(accA1[0], SCL, pa4[0]));
                const float f1 = __builtin_amdgcn_exp2f(fmaf(accA1[1], SCL, pa4[1]));
                const float f2 = __builtin_amdgcn_exp2f(fmaf(accA1[2], SCL, pa4[2]));
                const float f3 = __builtin_amdgcn_exp2f(fmaf(accA1[3], SCL, pa4[3]));
                const float f4 = __builtin_amdgcn_exp2f(fmaf(accB1[0], SCL, pb4[0]));
                const float f5 = __builtin_amdgcn_exp2f(fmaf(accB1[1], SCL, pb4[1]));
                const float f6 = __builtin_amdgcn_exp2f(fmaf(accB1[2], SCL, pb4[2]));
                const float f7 = __builtin_amdgcn_exp2f(fmaf(accB1[3], SCL, pb4[3]));
                union { f16x2 h2[4]; f16x8 v; } pu1;
                pu1.h2[0] = PKRTZ(f0, f1);
                pu1.h2[1] = PKRTZ(f2, f3);
                pu1.h2[2] = PKRTZ(f4, f5);
                pu1.h2[3] = PKRTZ(f6, f7);
                pfrag1 = pu1.v;
            }

            __builtin_amdgcn_s_setprio(1);
            psacc0 = MFMA16(pfrag0, ones, psacc0, 0, 0, 0);
            if (has2) psacc1 = MFMA16(pfrag1, ones, psacc1, 0, 0, 0);
            #pragma unroll
            for (int cg = 0; cg < 4; ++cg) {
                f16x8 vb = *(const f16x8*)(smem + VT_OFF + (cg * 16 + q16) * 848 + kc * 64 + g * 16);
                oc0[cg] = MFMA16(pfrag0, vb, oc0[cg], 0, 0, 0);
                if (has2) oc1[cg] = MFMA16(pfrag1, vb, oc1[cg], 0, 0, 0);
            }
            __builtin_amdgcn_s_setprio(0);
        }
        // tail: tile 24 (keys 384..399) via last prefetch; upper half zero pad
        {
            f32x4 pa4 = *(const f32x4*)(smem + PEN_OFF + (384 + 4 * g) * 4);
            f32x4 accA0 = {0.f, 0.f, 0.f, 0.f};
            accA0 = MFMA16(ka0, qreg0[0], accA0, 0, 0, 0);
            accA0 = MFMA16(ka1, qreg0[1], accA0, 0, 0, 0);
            const float e0 = __builtin_amdgcn_exp2f(fmaf(accA0[0], SCL, pa4[0]));
            const float e1 = __builtin_amdgcn_exp2f(fmaf(accA0[1], SCL, pa4[1]));
            const float e2 = __builtin_amdgcn_exp2f(fmaf(accA0[2], SCL, pa4[2]));
            const float e3 = __builtin_amdgcn_exp2f(fmaf(accA0[3], SCL, pa4[3]));
            union { f16x2 h2[4]; f16x8 v; } pu0;
            pu0.h2[0] = PKRTZ(e0, e1);
            pu0.h2[1] = PKRTZ(e2, e3);
            pu0.h2[2] = (f16x2){0, 0};
            pu0.h2[3] = (f16x2){0, 0};
            const f16x8 pfrag0 = pu0.v;

            f16x8 pfrag1;
            if (has2) {
                f32x4 accA1 = {0.f, 0.f, 0.f, 0.f};
                accA1 = MFMA16(ka0, qreg1[0], accA1, 0, 0, 0);
                accA1 = MFMA16(ka1, qreg1[1], accA1, 0, 0, 0);
                const float f0 = __builtin_amdgcn_exp2f(fmaf(accA1[0], SCL, pa4[0]));
                const float f1 = __builtin_amdgcn_exp2f(fmaf(accA1[1], SCL, pa4[1]));
                const float f2 = __builtin_amdgcn_exp2f(fmaf(accA1[2], SCL, pa4[2]));
                const float f3 = __builtin_amdgcn_exp2f(fmaf(accA1[3], SCL, pa4[3]));
                union { f16x2 h2[4]; f16x8 v; } pu1;
                pu1.h2[0] = PKRTZ(f0, f1);
                pu1.h2[1] = PKRTZ(f2, f3);
                pu1.h2[2] = (f16x2){0, 0};
                pu1.h2[3] = (f16x2){0, 0};
                pfrag1 = pu1.v;
            }
            psacc0 = MFMA16(pfrag0, ones, psacc0, 0, 0, 0);
            if (has2) psacc1 = MFMA16(pfrag1, ones, psacc1, 0, 0, 0);
            #pragma unroll
            for (int cg = 0; cg < 4; ++cg) {
                f16x8 vb = *(const f16x8*)(smem + VT_OFF + (cg * 16 + q16) * 848 + 12 * 64 + g * 16);
                oc0[cg] = MFMA16(pfrag0, vb, oc0[cg], 0, 0, 0);
                if (has2) oc1[cg] = MFMA16(pfrag1, vb, oc1[cg], 0, 0, 0);
            }
        }

        // epilogue: per-row scale directly from psacc (row i = 4g+r matches output row);
        // query-mask gate from the penalty table (pen > -1000 <=> mask bit set)
        {
            f32x4 penq0 = *(const f32x4*)(smem + PEN_OFF + (qt0 * 16 + 4 * g) * 4);
            float rs[4];
            #pragma unroll
            for (int r = 0; r < 4; ++r)
                rs[r] = (penq0[r] > -1000.f) ? __builtin_amdgcn_rcpf(psacc0[r]) : 0.0f;
            float* op0 = out + (size_t)(b * NQ + qt0 * 16) * DMODEL + h * 64;
            #pragma unroll
            for (int r = 0; r < 4; ++r) {
                #pragma unroll
                for (int cg = 0; cg < 4; ++cg)
                    op0[(4 * g + r) * DMODEL + cg * 16 + q16] = oc0[cg][r] * rs[r];
            }
            if (has2) {
                f32x4 penq1 = *(const f32x4*)(smem + PEN_OFF + (qt1 * 16 + 4 * g) * 4);
                #pragma unroll
                for (int r = 0; r < 4; ++r)
                    rs[r] = (penq1[r] > -1000.f) ? __builtin_amdgcn_rcpf(psacc1[r]) : 0.0f;
                float* op1 = out + (size_t)(b * NQ + qt1 * 16) * DMODEL + h * 64;
                #pragma unroll
                for (int r = 0; r < 4; ++r) {
                    #pragma unroll
                    for (int cg = 0; cg < 4; ++cg)
                        op1[(4 * g + r) * DMODEL + cg * 16 + q16] = oc1[cg][r] * rs[r];
                }
            }
        }
    }
}

extern "C" void kernel_launch(void* const* d_in, const int* in_sizes, int n_in,
                              void* d_out, int out_size, void* d_ws, size_t ws_size,
                              hipStream_t stream) {
    const float* R    = (const float*)d_in[0];
    const float* Rmas = (const float*)d_in[1];
    const float* Wq   = (const float*)d_in[2];
    const float* bq   = (const float*)d_in[3];
    const float* Wk   = (const float*)d_in[4];
    const float* bk   = (const float*)d_in[5];
    const float* Wv   = (const float*)d_in[6];
    const float* bv   = (const float*)d_in[7];
    float* out = (float*)d_out;

    (void)hipFuncSetAttribute(reinterpret_cast<const void*>(attn_fused),
                              hipFuncAttributeMaxDynamicSharedMemorySize, SMEM_BYTES);
    attn_fused<<<dim3(384), dim3(1024), SMEM_BYTES, stream>>>(R, Rmas, Wq, bq, Wk, bk, Wv, bv, out);
}

// Round 20
// 39.778 us; speedup vs baseline: 1.2697x; 1.0227x over previous
//
#include <hip/hip_runtime.h>

typedef float    f32x4 __attribute__((ext_vector_type(4)));
typedef _Float16 f16x8 __attribute__((ext_vector_type(8)));
typedef _Float16 f16x4 __attribute__((ext_vector_type(4)));
typedef _Float16 f16x2 __attribute__((ext_vector_type(2)));
typedef __fp16   fp16x2_raw __attribute__((ext_vector_type(2)));

#define MFMA16 __builtin_amdgcn_mfma_f32_16x16x32_f16

__device__ __forceinline__ f16x2 pkrtz(float a, float b) {
    fp16x2_raw t = __builtin_amdgcn_cvt_pkrtz(a, b);
    union { fp16x2_raw r; f16x2 h; } u;
    u.r = t;
    return u.h;
}
#define PKRTZ pkrtz

#define NQ     400
#define DMODEL 768

// streaming softmax, fixed offset: p = 2^(fma(S, SCL, pen[k]))
#define SCL 0.18033688011112042f   /* 0.125 * log2(e) */
#define PEN 18033.688011112043f    /* 12500 * log2(e) */
#define M0  8.0f

// LDS layout (bytes)
#define K_OFF    0                  // K fp16 [400][64perm], 128B rows, XOR-swizzled by (row&7)<<4
#define VT_OFF   51200              // V^T fp16 [64][424], 848B rows, k block-permuted; 54272B
#define W_OFF    105472             // W fp16 x3, [64] rows of 128B, XOR-swizzled; 24576B
#define PEN_OFF  130048             // f32[400] penalty table
#define BIAS_OFF 131648             // bias f32 [3][64]
#define MKB_OFF  132416             // mask bits, 16 u32
#define SMEM_BYTES 132480

__device__ __forceinline__ f16x8 cvt8(const float* rp) {
    f32x4 u0 = *(const f32x4*)(rp);
    f32x4 u1 = *(const f32x4*)(rp + 4);
    union { f16x2 h2[4]; f16x8 v; } u;
    u.h2[0] = PKRTZ(u0[0], u0[1]);
    u.h2[1] = PKRTZ(u0[2], u0[3]);
    u.h2[2] = PKRTZ(u1[0], u1[1]);
    u.h2[3] = PKRTZ(u1[2], u1[3]);
    return u.v;
}

// V projection (A=R-frag, B=Wv-frag) -> VT rows, b64 writes
__device__ __forceinline__ void proj_v(char* smem, f16x8 af0, f16x8 af1,
                                       int t, int g, int q16, int csw) {
    #pragma unroll
    for (int cg = 0; cg < 4; ++cg) {
        const int col = cg * 16 + q16;
        const float bb = *(const float*)(smem + BIAS_OFF + (128 + col) * 4);
        f32x4 acc = {bb, bb, bb, bb};
        f16x8 wb0 = *(const f16x8*)(smem + W_OFF + 16384 + col * 128 + ((g * 16) ^ csw));
        f16x8 wb1 = *(const f16x8*)(smem + W_OFF + 16384 + col * 128 + ((64 + g * 16) ^ csw));
        acc = MFMA16(af0, wb0, acc, 0, 0, 0);
        acc = MFMA16(af1, wb1, acc, 0, 0, 0);
        union { f16x2 h2[2]; f16x4 v; } hv;
        hv.h2[0] = PKRTZ(acc[0], acc[1]);
        hv.h2[1] = PKRTZ(acc[2], acc[3]);
        *(f16x4*)(smem + VT_OFF + col * 848 + (t >> 1) * 64 + g * 16 + (t & 1) * 8) = hv.v;
    }
}

// K projection (SWAPPED: A=Wk-frag, B=R-frag) -> K row kk, permuted cols, b64 writes
__device__ __forceinline__ void proj_k(char* smem, f16x8 af0, f16x8 af1,
                                       int kk, int g, int q16, int csw) {
    #pragma unroll
    for (int cg = 0; cg < 4; ++cg) {
        const int d0 = cg * 16 + 4 * g;
        f32x4 acc = *(const f32x4*)(smem + BIAS_OFF + (64 + d0) * 4);
        f16x8 wb0 = *(const f16x8*)(smem + W_OFF + 8192 + (cg * 16 + q16) * 128 + ((g * 16) ^ csw));
        f16x8 wb1 = *(const f16x8*)(smem + W_OFF + 8192 + (cg * 16 + q16) * 128 + ((64 + g * 16) ^ csw));
        acc = MFMA16(wb0, af0, acc, 0, 0, 0);   // C[d][q]
        acc = MFMA16(wb1, af1, acc, 0, 0, 0);
        union { f16x2 h2[2]; f16x4 v; } hv;
        hv.h2[0] = PKRTZ(acc[0], acc[1]);
        hv.h2[1] = PKRTZ(acc[2], acc[3]);
        const int pos2 = ((cg & 2) << 5) + g * 16 + (cg & 1) * 8;
        *(f16x4*)(smem + K_OFF + kk * 128 + (pos2 ^ csw)) = hv.v;
    }
}

// Q projection (SWAPPED) -> register B-fragments, permuted k-order
__device__ __forceinline__ void proj_q(char* smem, f16x8 af0, f16x8 af1,
                                       int g, int q16, int csw, f16x8 (&qreg)[2]) {
    f32x4 qa[4];
    #pragma unroll
    for (int cg = 0; cg < 4; ++cg) {
        const int d0 = cg * 16 + 4 * g;
        f32x4 acc = *(const f32x4*)(smem + BIAS_OFF + d0 * 4);
        f16x8 wb0 = *(const f16x8*)(smem + W_OFF + (cg * 16 + q16) * 128 + ((g * 16) ^ csw));
        f16x8 wb1 = *(const f16x8*)(smem + W_OFF + (cg * 16 + q16) * 128 + ((64 + g * 16) ^ csw));
        acc = MFMA16(wb0, af0, acc, 0, 0, 0);
        acc = MFMA16(wb1, af1, acc, 0, 0, 0);
        qa[cg] = acc;
    }
    union { f16x2 h2[4]; f16x8 v; } u0, u1;
    u0.h2[0] = PKRTZ(qa[0][0], qa[0][1]);
    u0.h2[1] = PKRTZ(qa[0][2], qa[0][3]);
    u0.h2[2] = PKRTZ(qa[1][0], qa[1][1]);
    u0.h2[3] = PKRTZ(qa[1][2], qa[1][3]);
    u1.h2[0] = PKRTZ(qa[2][0], qa[2][1]);
    u1.h2[1] = PKRTZ(qa[2][2], qa[2][3]);
    u1.h2[2] = PKRTZ(qa[3][0], qa[3][1]);
    u1.h2[3] = PKRTZ(qa[3][2], qa[3][3]);
    qreg[0] = u0.v;
    qreg[1] = u1.v;
}

__global__ __launch_bounds__(1024, 4)
void attn_fused(const float* __restrict__ R, const float* __restrict__ Rmas,
                const float* __restrict__ Wq, const float* __restrict__ bq,
                const float* __restrict__ Wk, const float* __restrict__ bk,
                const float* __restrict__ Wv, const float* __restrict__ bv,
                float* __restrict__ out)
{
    extern __shared__ char smem[];
    const int tid  = threadIdx.x;
    const int lane = tid & 63;
    const int wv   = tid >> 6;      // 0..15
    const int g    = lane >> 4;
    const int q16  = lane & 15;
    const int csw  = (q16 & 7) << 4;

    const int blk = blockIdx.x;
    const int b   = blk / 12;
    const int h   = blk % 12;

    // ---------- phase 0: stage W, bias, mask bits, penalty table; zero-pad VT ----------
    {
        if (tid < 768) {
            const int m   = tid >> 8;
            const int idx = tid & 255;
            const int row = idx >> 2;          // 0..63
            const int c0  = (idx & 3) << 4;    // 0,16,32,48
            const float* Wm = (m == 0 ? Wq : (m == 1 ? Wk : Wv)) + row * 64 + c0;
            const int sw = (row & 7) << 4;
            #pragma unroll
            for (int k2 = 0; k2 < 2; ++k2) {
                f32x4 v0 = *(const f32x4*)(Wm + 8 * k2);
                f32x4 v1 = *(const f32x4*)(Wm + 8 * k2 + 4);
                union { f16x2 h2[4]; f16x8 v; } hv;
                hv.h2[0] = PKRTZ(v0[0], v0[1]);
                hv.h2[1] = PKRTZ(v0[2], v0[3]);
                hv.h2[2] = PKRTZ(v1[0], v1[1]);
                hv.h2[3] = PKRTZ(v1[2], v1[3]);
                *(f16x8*)(smem + W_OFF + m * 8192 + row * 128 + ((c0 * 2 + 16 * k2) ^ sw)) = hv.v;
            }
        } else if (tid < 960) {
            const int jj = tid - 768;
            const float* bms[3] = {bq, bk, bv};
            *(float*)(smem + BIAS_OFF + jj * 4) = bms[jj >> 6][jj & 63];
        }
        if (wv < 7) {
            const int i = (wv << 6) | lane;
            const float mval = (i < NQ) ? Rmas[b * NQ + i] : 0.0f;
            unsigned long long bb = __ballot(mval != 0.0f);
            if (lane == 0) {
                ((unsigned*)(smem + MKB_OFF))[2 * wv]     = (unsigned)bb;
                ((unsigned*)(smem + MKB_OFF))[2 * wv + 1] = (unsigned)(bb >> 32);
            }
        }
        // penalty table straight from Rmas
        if (tid >= 512 && tid < 912) {
            const int k = tid - 512;
            *(float*)(smem + PEN_OFF + k * 4) =
                (Rmas[b * NQ + k] != 0.0f) ? -M0 : -(M0 + PEN);
        }
        if (tid < 256) {
            const int r = tid >> 2, c = tid & 3;
            *(f16x4*)(smem + VT_OFF + r * 848 + 768 + c * 16 + 8) = (f16x4){0, 0, 0, 0};
        }
    }
    __syncthreads();

    const float* Rbh = R + (size_t)b * NQ * DMODEL + h * 64;

    // ---------- phase 1: fused map — wave wv owns tiles {2wv, 2wv+1} for K, V AND Q ----------
    f16x8 qreg0[2], qreg1[2];
    const int qt0 = (2 * wv < 25)     ? (2 * wv)     : -1;
    const int qt1 = (2 * wv + 1 < 25) ? (2 * wv + 1) : -1;
    if (qt0 >= 0) {
        const float* rp = Rbh + (size_t)(qt0 * 16 + q16) * DMODEL + g * 8;
        f16x8 af0 = cvt8(rp);
        f16x8 af1 = cvt8(rp + 32);
        proj_k(smem, af0, af1, qt0 * 16 + q16, g, q16, csw);
        proj_v(smem, af0, af1, qt0, g, q16, csw);
        proj_q(smem, af0, af1, g, q16, csw, qreg0);
    }
    if (qt1 >= 0) {
        const float* rp = Rbh + (size_t)(qt1 * 16 + q16) * DMODEL + g * 8;
        f16x8 af0 = cvt8(rp);
        f16x8 af1 = cvt8(rp + 32);
        proj_k(smem, af0, af1, qt1 * 16 + q16, g, q16, csw);
        proj_v(smem, af0, af1, qt1, g, q16, csw);
        proj_q(smem, af0, af1, g, q16, csw, qreg1);
    }
    __syncthreads();

    // ---------- phase 2: dual-q-tile streaming attention with intra-wave
    //            MFMA/VALU overlap (PV0 issues while softmax1 runs) ----------
    if (qt0 >= 0) {
        const bool has2 = (qt1 >= 0);

        const int kbase = K_OFF + q16 * 128;
        const int o0 = (g * 16) ^ csw;
        const int o1 = (64 + g * 16) ^ csw;

        const f16x8 ones = {(_Float16)1.f, (_Float16)1.f, (_Float16)1.f, (_Float16)1.f,
                            (_Float16)1.f, (_Float16)1.f, (_Float16)1.f, (_Float16)1.f};

        f32x4 oc0[4], oc1[4];
        #pragma unroll
        for (int cg = 0; cg < 4; ++cg) {
            oc0[cg] = (f32x4){0.f, 0.f, 0.f, 0.f};
            oc1[cg] = (f32x4){0.f, 0.f, 0.f, 0.f};
        }
        f32x4 psacc0 = {0.f, 0.f, 0.f, 0.f};
        f32x4 psacc1 = {0.f, 0.f, 0.f, 0.f};

        // prefetch chunk 0: K tiles + pen
        f16x8 ka0 = *(const f16x8*)(smem + kbase + o0);
        f16x8 ka1 = *(const f16x8*)(smem + kbase + o1);
        f16x8 kb0 = *(const f16x8*)(smem + kbase + 2048 + o0);
        f16x8 kb1 = *(const f16x8*)(smem + kbase + 2048 + o1);
        f32x4 pa4 = *(const f32x4*)(smem + PEN_OFF + (4 * g) * 4);
        f32x4 pb4 = *(const f32x4*)(smem + PEN_OFF + (16 + 4 * g) * 4);

        #pragma unroll 1
        for (int kc = 0; kc < 12; ++kc) {
            // QK^T for both tiles
            __builtin_amdgcn_s_setprio(1);
            f32x4 accA0 = {0.f, 0.f, 0.f, 0.f};
            accA0 = MFMA16(ka0, qreg0[0], accA0, 0, 0, 0);
            accA0 = MFMA16(ka1, qreg0[1], accA0, 0, 0, 0);
            f32x4 accB0 = {0.f, 0.f, 0.f, 0.f};
            accB0 = MFMA16(kb0, qreg0[0], accB0, 0, 0, 0);
            accB0 = MFMA16(kb1, qreg0[1], accB0, 0, 0, 0);
            f32x4 accA1 = {0.f, 0.f, 0.f, 0.f};
            f32x4 accB1 = {0.f, 0.f, 0.f, 0.f};
            if (has2) {
                accA1 = MFMA16(ka0, qreg1[0], accA1, 0, 0, 0);
                accA1 = MFMA16(ka1, qreg1[1], accA1, 0, 0, 0);
                accB1 = MFMA16(kb0, qreg1[0], accB1, 0, 0, 0);
                accB1 = MFMA16(kb1, qreg1[1], accB1, 0, 0, 0);
            }
            __builtin_amdgcn_s_setprio(0);

            // prefetch next chunk's K (kc=11: tileA = tail rows 384..399; tileB unused pad)
            const char* kn = smem + kbase + (kc + 1) * 4096;
            ka0 = *(const f16x8*)(kn + o0);
            ka1 = *(const f16x8*)(kn + o1);
            kb0 = *(const f16x8*)(kn + 2048 + o0);
            kb1 = *(const f16x8*)(kn + 2048 + o1);

            // softmax tile 0
            const float e0 = __builtin_amdgcn_exp2f(fmaf(accA0[0], SCL, pa4[0]));
            const float e1 = __builtin_amdgcn_exp2f(fmaf(accA0[1], SCL, pa4[1]));
            const float e2 = __builtin_amdgcn_exp2f(fmaf(accA0[2], SCL, pa4[2]));
            const float e3 = __builtin_amdgcn_exp2f(fmaf(accA0[3], SCL, pa4[3]));
            const float e4 = __builtin_amdgcn_exp2f(fmaf(accB0[0], SCL, pb4[0]));
            const float e5 = __builtin_amdgcn_exp2f(fmaf(accB0[1], SCL, pb4[1]));
            const float e6 = __builtin_amdgcn_exp2f(fmaf(accB0[2], SCL, pb4[2]));
            const float e7 = __builtin_amdgcn_exp2f(fmaf(accB0[3], SCL, pb4[3]));
            union { f16x2 h2[4]; f16x8 v; } pu0;
            pu0.h2[0] = PKRTZ(e0, e1);
            pu0.h2[1] = PKRTZ(e2, e3);
            pu0.h2[2] = PKRTZ(e4, e5);
            pu0.h2[3] = PKRTZ(e6, e7);
            const f16x8 pfrag0 = pu0.v;

            // VT loads + PV0 + ps0: matrix pipe works while tile-1 softmax runs next
            f16x8 vb0 = *(const f16x8*)(smem + VT_OFF + (q16) * 848 + kc * 64 + g * 16);
            f16x8 vb1 = *(const f16x8*)(smem + VT_OFF + (16 + q16) * 848 + kc * 64 + g * 16);
            f16x8 vb2 = *(const f16x8*)(smem + VT_OFF + (32 + q16) * 848 + kc * 64 + g * 16);
            f16x8 vb3 = *(const f16x8*)(smem + VT_OFF + (48 + q16) * 848 + kc * 64 + g * 16);
            __builtin_amdgcn_s_setprio(1);
            psacc0 = MFMA16(pfrag0, ones, psacc0, 0, 0, 0);
            oc0[0] = MFMA16(pfrag0, vb0, oc0[0], 0, 0, 0);
            oc0[1] = MFMA16(pfrag0, vb1, oc0[1], 0, 0, 0);
            oc0[2] = MFMA16(pfrag0, vb2, oc0[2], 0, 0, 0);
            oc0[3] = MFMA16(pfrag0, vb3, oc0[3], 0, 0, 0);
            __builtin_amdgcn_s_setprio(0);

            if (has2) {
                // softmax tile 1 (overlaps PV0 execution)
                const float f0 = __builtin_amdgcn_exp2f(fmaf(accA1[0], SCL, pa4[0]));
                const float f1 = __builtin_amdgcn_exp2f(fmaf(accA1[1], SCL, pa4[1]));
                const float f2 = __builtin_amdgcn_exp2f(fmaf(accA1[2], SCL, pa4[2]));
                const float f3 = __builtin_amdgcn_exp2f(fmaf(accA1[3], SCL, pa4[3]));
                const float f4 = __builtin_amdgcn_exp2f(fmaf(accB1[0], SCL, pb4[0]));
                const float f5 = __builtin_amdgcn_exp2f(fmaf(accB1[1], SCL, pb4[1]));
                const float f6 = __builtin_amdgcn_exp2f(fmaf(accB1[2], SCL, pb4[2]));
                const float f7 = __builtin_amdgcn_exp2f(fmaf(accB1[3], SCL, pb4[3]));
                union { f16x2 h2[4]; f16x8 v; } pu1;
                pu1.h2[0] = PKRTZ(f0, f1);
                pu1.h2[1] = PKRTZ(f2, f3);
                pu1.h2[2] = PKRTZ(f4, f5);
                pu1.h2[3] = PKRTZ(f6, f7);
                const f16x8 pfrag1 = pu1.v;
                __builtin_amdgcn_s_setprio(1);
                psacc1 = MFMA16(pfrag1, ones, psacc1, 0, 0, 0);
                oc1[0] = MFMA16(pfrag1, vb0, oc1[0], 0, 0, 0);
                oc1[1] = MFMA16(pfrag1, vb1, oc1[1], 0, 0, 0);
                oc1[2] = MFMA16(pfrag1, vb2, oc1[2], 0, 0, 0);
                oc1[3] = MFMA16(pfrag1, vb3, oc1[3], 0, 0, 0);
                __builtin_amdgcn_s_setprio(0);
            }

            // rotate pen for next chunk (kc=11 -> pa4 = tail pen[384..]; pb4 harmless)
            pa4 = *(const f32x4*)(smem + PEN_OFF + ((kc + 1) * 32 + 4 * g) * 4);
            pb4 = *(const f32x4*)(smem + PEN_OFF + ((kc + 1) * 32 + 16 + 4 * g) * 4);
        }
        // tail: tile 24 (keys 384..399); uses rotated pa4; upper half is VT zero pad
        {
            f32x4 accA0 = {0.f, 0.f, 0.f, 0.f};
            accA0 = MFMA16(ka0, qreg0[0], accA0, 0, 0, 0);
            accA0 = MFMA16(ka1, qreg0[1], accA0, 0, 0, 0);
            f32x4 accA1 = {0.f, 0.f, 0.f, 0.f};
            if (has2) {
                accA1 = MFMA16(ka0, qreg1[0], accA1, 0, 0, 0);
                accA1 = MFMA16(ka1, qreg1[1], accA1, 0, 0, 0);
            }
            const float e0 = __builtin_amdgcn_exp2f(fmaf(accA0[0], SCL, pa4[0]));
            const float e1 = __builtin_amdgcn_exp2f(fmaf(accA0[1], SCL, pa4[1]));
            const float e2 = __builtin_amdgcn_exp2f(fmaf(accA0[2], SCL, pa4[2]));
            const float e3 = __builtin_amdgcn_exp2f(fmaf(accA0[3], SCL, pa4[3]));
            union { f16x2 h2[4]; f16x8 v; } pu0;
            pu0.h2[0] = PKRTZ(e0, e1);
            pu0.h2[1] = PKRTZ(e2, e3);
            pu0.h2[2] = (f16x2){0, 0};
            pu0.h2[3] = (f16x2){0, 0};
            const f16x8 pfrag0 = pu0.v;

            f16x8 vb0 = *(const f16x8*)(smem + VT_OFF + (q16) * 848 + 12 * 64 + g * 16);
            f16x8 vb1 = *(const f16x8*)(smem + VT_OFF + (16 + q16) * 848 + 12 * 64 + g * 16);
            f16x8 vb2 = *(const f16x8*)(smem + VT_OFF + (32 + q16) * 848 + 12 * 64 + g * 16);
            f16x8 vb3 = *(const f16x8*)(smem + VT_OFF + (48 + q16) * 848 + 12 * 64 + g * 16);
            psacc0 = MFMA16(pfrag0, ones, psacc0, 0, 0, 0);
            oc0[0] = MFMA16(pfrag0, vb0, oc0[0], 0, 0, 0);
            oc0[1] = MFMA16(pfrag0, vb1, oc0[1], 0, 0, 0);
            oc0[2] = MFMA16(pfrag0, vb2, oc0[2], 0, 0, 0);
            oc0[3] = MFMA16(pfrag0, vb3, oc0[3], 0, 0, 0);

            if (has2) {
                const float f0 = __builtin_amdgcn_exp2f(fmaf(accA1[0], SCL, pa4[0]));
                const float f1 = __builtin_amdgcn_exp2f(fmaf(accA1[1], SCL, pa4[1]));
                const float f2 = __builtin_amdgcn_exp2f(fmaf(accA1[2], SCL, pa4[2]));
                const float f3 = __builtin_amdgcn_exp2f(fmaf(accA1[3], SCL, pa4[3]));
                union { f16x2 h2[4]; f16x8 v; } pu1;
                pu1.h2[0] = PKRTZ(f0, f1);
                pu1.h2[1] = PKRTZ(f2, f3);
                pu1.h2[2] = (f16x2){0, 0};
                pu1.h2[3] = (f16x2){0, 0};
                const f16x8 pfrag1 = pu1.v;
                psacc1 = MFMA16(pfrag1, ones, psacc1, 0, 0, 0);
                oc1[0] = MFMA16(pfrag1, vb0, oc1[0], 0, 0, 0);
                oc1[1] = MFMA16(pfrag1, vb1, oc1[1], 0, 0, 0);
                oc1[2] = MFMA16(pfrag1, vb2, oc1[2], 0, 0, 0);
                oc1[3] = MFMA16(pfrag1, vb3, oc1[3], 0, 0, 0);
            }
        }

        // epilogue: per-row scale from psacc (row i = 4g+r); mask gate via pen table
        {
            f32x4 penq0 = *(const f32x4*)(smem + PEN_OFF + (qt0 * 16 + 4 * g) * 4);
            float rs[4];
            #pragma unroll
            for (int r = 0; r < 4; ++r)
                rs[r] = (penq0[r] > -1000.f) ? __builtin_amdgcn_rcpf(psacc0[r]) : 0.0f;
            float* op0 = out + (size_t)(b * NQ + qt0 * 16) * DMODEL + h * 64;
            #pragma unroll
            for (int r = 0; r < 4; ++r) {
                #pragma unroll
                for (int cg = 0; cg < 4; ++cg)
                    op0[(4 * g + r) * DMODEL + cg * 16 + q16] = oc0[cg][r] * rs[r];
            }
            if (has2) {
                f32x4 penq1 = *(const f32x4*)(smem + PEN_OFF + (qt1 * 16 + 4 * g) * 4);
                #pragma unroll
                for (int r = 0; r < 4; ++r)
                    rs[r] = (penq1[r] > -1000.f) ? __builtin_amdgcn_rcpf(psacc1[r]) : 0.0f;
                float* op1 = out + (size_t)(b * NQ + qt1 * 16) * DMODEL + h * 64;
                #pragma unroll
                for (int r = 0; r < 4; ++r) {
                    #pragma unroll
                    for (int cg = 0; cg < 4; ++cg)
                        op1[(4 * g + r) * DMODEL + cg * 16 + q16] = oc1[cg][r] * rs[r];
                }
            }
        }
    }
}

extern "C" void kernel_launch(void* const* d_in, const int* in_sizes, int n_in,
                              void* d_out, int out_size, void* d_ws, size_t ws_size,
                              hipStream_t stream) {
    const float* R    = (const float*)d_in[0];
    const float* Rmas = (const float*)d_in[1];
    const float* Wq   = (const float*)d_in[2];
    const float* bq   = (const float*)d_in[3];
    const float* Wk   = (const float*)d_in[4];
    const float* bk   = (const float*)d_in[5];
    const float* Wv   = (const float*)d_in[6];
    const float* bv   = (const float*)d_in[7];
    float* out = (float*)d_out;

    (void)hipFuncSetAttribute(reinterpret_cast<const void*>(attn_fused),
                              hipFuncAttributeMaxDynamicSharedMemorySize, SMEM_BYTES);
    attn_fused<<<dim3(384), dim3(1024), SMEM_BYTES, stream>>>(R, Rmas, Wq, bq, Wk, bk, Wv, bv, out);
}